// Round 11
// baseline (293.274 us; speedup 1.0000x reference)
//
#include <hip/hip_runtime.h>

typedef unsigned short u16;
typedef __bf16 bf16_t;
typedef bf16_t bf16x8 __attribute__((ext_vector_type(8)));
typedef float f32x4 __attribute__((ext_vector_type(4)));

#define B_   8
#define CH   64
#define HW   2304
#define L2E  1.4426950408889634f

// ---- workspace byte offsets ----
#define OFF_XLC   0u          // bf16 [8][64][2304] channel-major
#define OFF_XRC   2359296u
#define OFF_XLT   4718592u    // bf16 [8][2304][64] position-major
#define OFF_XRT   7077888u
#define OFF_B1    9437184u    // f32  [8][64][2304]
#define OFF_B2    14155776u
#define OFF_RS2   18874368u   // f32  [8][2304]  1/S2[n]
// total 18948096 bytes

__device__ __forceinline__ float bf2f(u16 u){
  union { unsigned int i; float f; } v; v.i = ((unsigned int)u) << 16; return v.f;
}
__device__ __forceinline__ u16 f2bf(float f){
  union { float f; unsigned int i; } v; v.f = f;
  unsigned int r = v.i + 0x7FFFu + ((v.i >> 16) & 1u);
  return (u16)(r >> 16);
}

// ---------------- K1: xL/xR = W[64x128] @ concat(x_h,x_l) + b ----------------
// grid (9, 4, 16): p = bx*256+t, o0 = by*16, (b,side) = (bz>>1, bz&1)
__global__ __launch_bounds__(256) void k_proj(
    const float* xlh, const float* xll, const float* xrh, const float* xrl,
    const float* wLl, const float* bLl, const float* wRr, const float* bRr,
    char* ws)
{
  int p  = blockIdx.x*256 + threadIdx.x;
  int o0 = blockIdx.y*16;
  int b  = blockIdx.z >> 1, side = blockIdx.z & 1;
  const float* xh = (side ? xrh : xlh) + (size_t)b*CH*HW;
  const float* xl = (side ? xrl : xll) + (size_t)b*CH*HW;
  const float* w  = (side ? wRr : wLl);
  const float* bi = (side ? bRr : bLl);

  float acc[16];
  #pragma unroll
  for (int j=0;j<16;j++) acc[j] = bi[o0+j];
  for (int c=0;c<64;c++){
    float xv = xh[(size_t)c*HW + p];
    #pragma unroll
    for (int j=0;j<16;j++) acc[j] = fmaf(w[(size_t)(o0+j)*128 + c], xv, acc[j]);
  }
  for (int c=0;c<64;c++){
    float xv = xl[(size_t)c*HW + p];
    #pragma unroll
    for (int j=0;j<16;j++) acc[j] = fmaf(w[(size_t)(o0+j)*128 + 64 + c], xv, acc[j]);
  }
  u16* xc = (u16*)(ws + (side ? OFF_XRC : OFF_XLC)) + (size_t)b*CH*HW;
  u16* xt = (u16*)(ws + (side ? OFF_XRT : OFF_XLT)) + (size_t)b*HW*CH;
  unsigned int pk[8];
  #pragma unroll
  for (int j=0;j<8;j++){
    unsigned int lo16 = f2bf(acc[2*j]);
    unsigned int hi16 = f2bf(acc[2*j+1]);
    pk[j] = lo16 | (hi16 << 16);
    xc[(size_t)(o0+2*j  )*HW + p] = (u16)lo16;
    xc[(size_t)(o0+2*j+1)*HW + p] = (u16)hi16;
  }
  uint4* dst = (uint4*)&xt[(size_t)p*CH + o0];
  dst[0] = make_uint4(pk[0],pk[1],pk[2],pk[3]);
  dst[1] = make_uint4(pk[4],pk[5],pk[6],pk[7]);
}

// ---------------- K2: 1/S2[n]; 32 rows/block, 8 waves x m-eighth, prefetch ----------------
// grid (72, 8), 512 threads
__global__ __launch_bounds__(512, 4) void k_stats(char* ws)
{
  __shared__ float part[8][2][4][4];
  int b = blockIdx.y;
  const u16* X = (const u16*)(ws + OFF_XLT) + (size_t)b*HW*CH;   // rows n
  const u16* Y = (const u16*)(ws + OFF_XRT) + (size_t)b*HW*CH;   // reduce over m
  float* out = (float*)(ws + OFF_RS2) + b*HW;

  int lane = threadIdx.x & 63;
  int wv   = __builtin_amdgcn_readfirstlane(threadIdx.x >> 6);
  int lo = lane & 15, g = lane >> 4;
  int r0 = blockIdx.x*32;

  bf16x8 aA0 = *(const bf16x8*)&X[(size_t)(r0+lo)*CH + 8*g];
  bf16x8 aA1 = *(const bf16x8*)&X[(size_t)(r0+lo)*CH + 32 + 8*g];
  bf16x8 aB0 = *(const bf16x8*)&X[(size_t)(r0+16+lo)*CH + 8*g];
  bf16x8 aB1 = *(const bf16x8*)&X[(size_t)(r0+16+lo)*CH + 32 + 8*g];

  float sA[4] = {0.f,0.f,0.f,0.f};
  float sB[4] = {0.f,0.f,0.f,0.f};
  int jb = wv * 288;

  bf16x8 b0 = *(const bf16x8*)&Y[(size_t)(jb+lo)*CH + 8*g];
  bf16x8 b1 = *(const bf16x8*)&Y[(size_t)(jb+lo)*CH + 32 + 8*g];
  for (int i = 0; i < 18; ++i){
    int jn = jb + ((i+1 < 18) ? (i+1)*16 : 0);
    bf16x8 nb0 = *(const bf16x8*)&Y[(size_t)(jn+lo)*CH + 8*g];
    bf16x8 nb1 = *(const bf16x8*)&Y[(size_t)(jn+lo)*CH + 32 + 8*g];
    f32x4 z4 = {0.f,0.f,0.f,0.f};
    f32x4 dA = __builtin_amdgcn_mfma_f32_16x16x32_bf16(aA0, b0, z4, 0,0,0);
    dA = __builtin_amdgcn_mfma_f32_16x16x32_bf16(aA1, b1, dA, 0,0,0);
    f32x4 dB = __builtin_amdgcn_mfma_f32_16x16x32_bf16(aB0, b0, z4, 0,0,0);
    dB = __builtin_amdgcn_mfma_f32_16x16x32_bf16(aB1, b1, dB, 0,0,0);
    #pragma unroll
    for (int r=0;r<4;r++){ sA[r] += exp2f(dA[r]*L2E); sB[r] += exp2f(dB[r]*L2E); }
    b0 = nb0; b1 = nb1;
  }
  #pragma unroll
  for (int mask = 1; mask < 16; mask <<= 1){
    #pragma unroll
    for (int r=0;r<4;r++){ sA[r] += __shfl_xor(sA[r], mask, 64); sB[r] += __shfl_xor(sB[r], mask, 64); }
  }
  if (lo == 0){
    #pragma unroll
    for (int r=0;r<4;r++){ part[wv][0][g][r] = sA[r]; part[wv][1][g][r] = sB[r]; }
  }
  __syncthreads();
  if (threadIdx.x < 32){
    int t = threadIdx.x;
    int half = t >> 4, gg = (t & 15) >> 2, rr = t & 3;
    float sum = 0.f;
    #pragma unroll
    for (int w8=0; w8<8; ++w8) sum += part[w8][half][gg][rr];
    out[r0 + 16*half + 4*gg + rr] = 1.0f / sum;
  }
}

// ---------------- K3 helpers ----------------
__device__ __forceinline__ void attn_compute(
    const bf16x8& fa00, const bf16x8& fa01, const bf16x8& fa10, const bf16x8& fa11,
    const bf16x8& bL0, const bf16x8& bL1, const bf16x8& bL2, const bf16x8& bL3,
    const bf16x8& bR0, const bf16x8& bR1, const bf16x8& bR2, const bf16x8& bR3,
    const f32x4& r20, const f32x4& r21,
    const bf16x8& fmA0, const bf16x8& fmA1, const bf16x8& fmB0, const bf16x8& fmB1,
    f32x4 acc1A[4], f32x4 acc2A[4], f32x4 acc1B[4], f32x4 acc2B[4],
    float& s1A, float& s1B)
{
  f32x4 z4 = {0.f,0.f,0.f,0.f};
  f32x4 d0A = __builtin_amdgcn_mfma_f32_16x16x32_bf16(fa00, fmA0, z4, 0,0,0);
  d0A = __builtin_amdgcn_mfma_f32_16x16x32_bf16(fa01, fmA1, d0A, 0,0,0);
  f32x4 d1A = __builtin_amdgcn_mfma_f32_16x16x32_bf16(fa10, fmA0, z4, 0,0,0);
  d1A = __builtin_amdgcn_mfma_f32_16x16x32_bf16(fa11, fmA1, d1A, 0,0,0);
  f32x4 d0B = __builtin_amdgcn_mfma_f32_16x16x32_bf16(fa00, fmB0, z4, 0,0,0);
  d0B = __builtin_amdgcn_mfma_f32_16x16x32_bf16(fa01, fmB1, d0B, 0,0,0);
  f32x4 d1B = __builtin_amdgcn_mfma_f32_16x16x32_bf16(fa10, fmB0, z4, 0,0,0);
  d1B = __builtin_amdgcn_mfma_f32_16x16x32_bf16(fa11, fmB1, d1B, 0,0,0);

  bf16x8 pa1A, pa2A, pa1B, pa2B;
  #pragma unroll
  for (int r=0;r<4;r++){
    float e0 = exp2f(d0A[r]*L2E);
    float e1 = exp2f(d1A[r]*L2E);
    s1A += e0 + e1;
    pa1A[r]   = (bf16_t)e0;            // unnormalized; 1/S1 applied at writeout
    pa1A[r+4] = (bf16_t)e1;
    pa2A[r]   = (bf16_t)(e0 * r20[r]); // 1/S2[n] applied per-lane
    pa2A[r+4] = (bf16_t)(e1 * r21[r]);
    float f0 = exp2f(d0B[r]*L2E);
    float f1 = exp2f(d1B[r]*L2E);
    s1B += f0 + f1;
    pa1B[r]   = (bf16_t)f0;
    pa1B[r+4] = (bf16_t)f1;
    pa2B[r]   = (bf16_t)(f0 * r20[r]);
    pa2B[r+4] = (bf16_t)(f1 * r21[r]);
  }
  acc1A[0] = __builtin_amdgcn_mfma_f32_16x16x32_bf16(pa1A, bL0, acc1A[0], 0,0,0);
  acc1A[1] = __builtin_amdgcn_mfma_f32_16x16x32_bf16(pa1A, bL1, acc1A[1], 0,0,0);
  acc1A[2] = __builtin_amdgcn_mfma_f32_16x16x32_bf16(pa1A, bL2, acc1A[2], 0,0,0);
  acc1A[3] = __builtin_amdgcn_mfma_f32_16x16x32_bf16(pa1A, bL3, acc1A[3], 0,0,0);
  acc2A[0] = __builtin_amdgcn_mfma_f32_16x16x32_bf16(pa2A, bR0, acc2A[0], 0,0,0);
  acc2A[1] = __builtin_amdgcn_mfma_f32_16x16x32_bf16(pa2A, bR1, acc2A[1], 0,0,0);
  acc2A[2] = __builtin_amdgcn_mfma_f32_16x16x32_bf16(pa2A, bR2, acc2A[2], 0,0,0);
  acc2A[3] = __builtin_amdgcn_mfma_f32_16x16x32_bf16(pa2A, bR3, acc2A[3], 0,0,0);
  acc1B[0] = __builtin_amdgcn_mfma_f32_16x16x32_bf16(pa1B, bL0, acc1B[0], 0,0,0);
  acc1B[1] = __builtin_amdgcn_mfma_f32_16x16x32_bf16(pa1B, bL1, acc1B[1], 0,0,0);
  acc1B[2] = __builtin_amdgcn_mfma_f32_16x16x32_bf16(pa1B, bL2, acc1B[2], 0,0,0);
  acc1B[3] = __builtin_amdgcn_mfma_f32_16x16x32_bf16(pa1B, bL3, acc1B[3], 0,0,0);
  acc2B[0] = __builtin_amdgcn_mfma_f32_16x16x32_bf16(pa2B, bR0, acc2B[0], 0,0,0);
  acc2B[1] = __builtin_amdgcn_mfma_f32_16x16x32_bf16(pa2B, bR1, acc2B[1], 0,0,0);
  acc2B[2] = __builtin_amdgcn_mfma_f32_16x16x32_bf16(pa2B, bR2, acc2B[2], 0,0,0);
  acc2B[3] = __builtin_amdgcn_mfma_f32_16x16x32_bf16(pa2B, bR3, acc2B[3], 0,0,0);
}

#define ATTN_LOAD(S, n0) \
  fa00##S = *(const bf16x8*)&XLt[(size_t)((n0)+pr  )*CH +      8*g]; \
  fa01##S = *(const bf16x8*)&XLt[(size_t)((n0)+pr  )*CH + 32 + 8*g]; \
  fa10##S = *(const bf16x8*)&XLt[(size_t)((n0)+pr+4)*CH +      8*g]; \
  fa11##S = *(const bf16x8*)&XLt[(size_t)((n0)+pr+4)*CH + 32 + 8*g]; \
  bL0##S = *(const bf16x8*)&XLc[(size_t)( 0+lo)*HW + (n0) + 8*g];    \
  bL1##S = *(const bf16x8*)&XLc[(size_t)(16+lo)*HW + (n0) + 8*g];    \
  bL2##S = *(const bf16x8*)&XLc[(size_t)(32+lo)*HW + (n0) + 8*g];    \
  bL3##S = *(const bf16x8*)&XLc[(size_t)(48+lo)*HW + (n0) + 8*g];    \
  bR0##S = *(const bf16x8*)&XRc[(size_t)( 0+lo)*HW + (n0) + 8*g];    \
  bR1##S = *(const bf16x8*)&XRc[(size_t)(16+lo)*HW + (n0) + 8*g];    \
  bR2##S = *(const bf16x8*)&XRc[(size_t)(32+lo)*HW + (n0) + 8*g];    \
  bR3##S = *(const bf16x8*)&XRc[(size_t)(48+lo)*HW + (n0) + 8*g];    \
  r20##S = *(const f32x4*)&rs2[(n0) + 8*g];                          \
  r21##S = *(const f32x4*)&rs2[(n0) + 8*g + 4];

// ---------------- K3: fused aff->P -> b1^T/b2^T; 32 m/block, 8 waves x n-eighth ----------------
// grid (72, 8), 512 threads: wave wv covers n in [wv*288, wv*288+288) = 9 steps of 32
__global__ __launch_bounds__(512, 4) void k_attn(char* ws)
{
  __shared__ float red[8][64][17];
  __shared__ float s1part[8][32];
  __shared__ float rs1inv[32];
  int b    = blockIdx.y;
  int lane = threadIdx.x & 63;
  int wv   = __builtin_amdgcn_readfirstlane(threadIdx.x >> 6);
  int lo = lane & 15, g = lane >> 4;
  int m0 = blockIdx.x * 32;

  const u16* XLt = (const u16*)(ws + OFF_XLT) + (size_t)b*HW*CH;
  const u16* XRt = (const u16*)(ws + OFF_XRT) + (size_t)b*HW*CH;
  const u16* XLc = (const u16*)(ws + OFF_XLC) + (size_t)b*CH*HW;
  const u16* XRc = (const u16*)(ws + OFF_XRC) + (size_t)b*CH*HW;
  const float* rs2 = (const float*)(ws + OFF_RS2) + b*HW;

  bf16x8 fmA0 = *(const bf16x8*)&XRt[(size_t)(m0+lo)*CH + 8*g];
  bf16x8 fmA1 = *(const bf16x8*)&XRt[(size_t)(m0+lo)*CH + 32 + 8*g];
  bf16x8 fmB0 = *(const bf16x8*)&XRt[(size_t)(m0+16+lo)*CH + 8*g];
  bf16x8 fmB1 = *(const bf16x8*)&XRt[(size_t)(m0+16+lo)*CH + 32 + 8*g];

  int pr = ((lo >> 2) << 3) + (lo & 3);

  f32x4 acc1A[4], acc2A[4], acc1B[4], acc2B[4];
  #pragma unroll
  for (int ct=0;ct<4;ct++){
    f32x4 z4 = {0.f,0.f,0.f,0.f};
    acc1A[ct]=z4; acc2A[ct]=z4; acc1B[ct]=z4; acc2B[ct]=z4;
  }
  float s1A = 0.f, s1B = 0.f;

  int nbeg = wv * 288;
  bf16x8 fa00X, fa01X, fa10X, fa11X, bL0X, bL1X, bL2X, bL3X, bR0X, bR1X, bR2X, bR3X;
  bf16x8 fa00Y, fa01Y, fa10Y, fa11Y, bL0Y, bL1Y, bL2Y, bL3Y, bR0Y, bR1Y, bR2Y, bR3Y;
  f32x4 r20X, r21X, r20Y, r21Y;

  ATTN_LOAD(X, nbeg)
  for (int s = 0; s < 8; s += 2){
    ATTN_LOAD(Y, nbeg + (s+1)*32)
    attn_compute(fa00X,fa01X,fa10X,fa11X, bL0X,bL1X,bL2X,bL3X, bR0X,bR1X,bR2X,bR3X,
                 r20X,r21X, fmA0,fmA1,fmB0,fmB1, acc1A,acc2A,acc1B,acc2B, s1A,s1B);
    ATTN_LOAD(X, nbeg + (s+2)*32)
    attn_compute(fa00Y,fa01Y,fa10Y,fa11Y, bL0Y,bL1Y,bL2Y,bL3Y, bR0Y,bR1Y,bR2Y,bR3Y,
                 r20Y,r21Y, fmA0,fmA1,fmB0,fmB1, acc1A,acc2A,acc1B,acc2B, s1A,s1B);
  }
  attn_compute(fa00X,fa01X,fa10X,fa11X, bL0X,bL1X,bL2X,bL3X, bR0X,bR1X,bR2X,bR3X,
               r20X,r21X, fmA0,fmA1,fmB0,fmB1, acc1A,acc2A,acc1B,acc2B, s1A,s1B);

  // ---- S1 block reduction ----
  s1A += __shfl_xor(s1A, 16, 64);  s1A += __shfl_xor(s1A, 32, 64);
  s1B += __shfl_xor(s1B, 16, 64);  s1B += __shfl_xor(s1B, 32, 64);
  if (lane < 16){ s1part[wv][lane] = s1A; s1part[wv][16+lane] = s1B; }
  __syncthreads();
  if (threadIdx.x < 32){
    int t = threadIdx.x;
    float s = 0.f;
    #pragma unroll
    for (int w8=0; w8<8; ++w8) s += s1part[w8][t];
    rs1inv[t] = 1.0f / s;
  }
  __syncthreads();

  float* B1 = (float*)(ws + OFF_B1) + (size_t)b*CH*HW;
  float* B2 = (float*)(ws + OFF_B2) + (size_t)b*CH*HW;
  int rl = threadIdx.x & 63;
  int rv = threadIdx.x >> 6;          // 0..7

  // 4 reduce phases: acc1A (scaled), acc2A, acc1B (scaled), acc2B
  #pragma unroll
  for (int v=0; v<16; ++v) red[wv][lane][v] = acc1A[v>>2][v&3];
  __syncthreads();
  #pragma unroll
  for (int k=0;k<2;k++){
    int v = rv + 8*k;
    float s = 0.f;
    #pragma unroll
    for (int w8=0; w8<8; ++w8) s += red[w8][rl][v];
    int midx = ((rl>>4)<<2) + (v&3);
    int c = ((v>>2)<<4) + (rl & 15);
    B1[(size_t)c*HW + m0 + midx] = s * rs1inv[midx];
  }
  __syncthreads();
  #pragma unroll
  for (int v=0; v<16; ++v) red[wv][lane][v] = acc2A[v>>2][v&3];
  __syncthreads();
  #pragma unroll
  for (int k=0;k<2;k++){
    int v = rv + 8*k;
    float s = 0.f;
    #pragma unroll
    for (int w8=0; w8<8; ++w8) s += red[w8][rl][v];
    int midx = ((rl>>4)<<2) + (v&3);
    int c = ((v>>2)<<4) + (rl & 15);
    B2[(size_t)c*HW + m0 + midx] = s;
  }
  __syncthreads();
  #pragma unroll
  for (int v=0; v<16; ++v) red[wv][lane][v] = acc1B[v>>2][v&3];
  __syncthreads();
  #pragma unroll
  for (int k=0;k<2;k++){
    int v = rv + 8*k;
    float s = 0.f;
    #pragma unroll
    for (int w8=0; w8<8; ++w8) s += red[w8][rl][v];
    int midx = ((rl>>4)<<2) + (v&3);
    int c = ((v>>2)<<4) + (rl & 15);
    B1[(size_t)c*HW + m0 + 16 + midx] = s * rs1inv[16 + midx];
  }
  __syncthreads();
  #pragma unroll
  for (int v=0; v<16; ++v) red[wv][lane][v] = acc2B[v>>2][v&3];
  __syncthreads();
  #pragma unroll
  for (int k=0;k<2;k++){
    int v = rv + 8*k;
    float s = 0.f;
    #pragma unroll
    for (int w8=0; w8<8; ++w8) s += red[w8][rl][v];
    int midx = ((rl>>4)<<2) + (v&3);
    int c = ((v>>2)<<4) + (rl & 15);
    B2[(size_t)c*HW + m0 + 16 + midx] = s;
  }
}

// ---------------- K4: gate + output convs (raw f32 weights), f32 OUTPUT ----------------
// grid (36, 2, 8): p-tile of 64, side, batch
__global__ __launch_bounds__(256) void k_out(
    char* ws,
    const float* gwL, const float* gbL, const float* gwR, const float* gbR,
    const float* wLo, const float* bLoi, const float* wRo, const float* bRoi,
    float* out)
{
  __shared__ float xT[64][64];
  __shared__ float bT[64][64];
  __shared__ float gpart[4][64];
  __shared__ float gLds[64];
  int t = threadIdx.x;
  int p0 = blockIdx.x*64;
  int side = blockIdx.y;
  int b = blockIdx.z;
  const float* braw = (const float*)(ws + (side ? OFF_B2 : OFF_B1)) + (size_t)b*CH*HW;
  const u16*   xc   = (const u16*)(ws + (side ? OFF_XRC : OFF_XLC)) + (size_t)b*CH*HW;
  const float* w    = side ? wRo : wLo;
  const float* gw   = side ? gwR : gwL;
  float        gb   = side ? gbR[0] : gbL[0];
  const float* bias = side ? bRoi : bLoi;

  #pragma unroll
  for (int i=0;i<16;i++){
    int flat = i*256 + t;
    int c = flat >> 6, pl = flat & 63;
    bT[c][pl] = braw[(size_t)c*HW + p0 + pl];
    xT[c][pl] = bf2f(xc[(size_t)c*HW + p0 + pl]);
  }
  __syncthreads();
  {
    int q = t >> 6, pl = t & 63;
    float a = 0.f;
    #pragma unroll
    for (int c = 0; c < 16; c++) a = fmaf(gw[16*q + c], bT[16*q + c][pl], a);
    gpart[q][pl] = a;
  }
  __syncthreads();
  if (t < 64){
    float x = gpart[0][t]+gpart[1][t]+gpart[2][t]+gpart[3][t] + gb;
    gLds[t] = 1.0f/(1.0f + exp2f(-x*L2E));    // sigmoid
  }
  __syncthreads();
  #pragma unroll
  for (int i=0;i<16;i++){
    int flat = i*256 + t;
    int c = flat >> 6, pl = flat & 63;
    bT[c][pl] *= gLds[pl];
  }
  __syncthreads();
  int wv = t >> 6;
  int lane = t & 63;
  float* outp = out + ((size_t)side*B_ + b)*CH*HW;
  for (int oi=0; oi<16; oi++){
    int o = wv*16 + oi;
    float a = bias[o];
    #pragma unroll 8
    for (int c=0;c<64;c++){
      a = fmaf(w[o*128 + c],      xT[c][lane], a);
      a = fmaf(w[o*128 + 64 + c], bT[c][lane], a);
    }
    outp[(size_t)o*HW + p0 + lane] = a;
  }
}

extern "C" void kernel_launch(void* const* d_in, const int* in_sizes, int n_in,
                              void* d_out, int out_size, void* d_ws, size_t ws_size,
                              hipStream_t stream)
{
  char* ws = (char*)d_ws;
  k_proj <<<dim3(9,4,16), 256, 0, stream>>>(
      (const float*)d_in[0], (const float*)d_in[1],
      (const float*)d_in[2], (const float*)d_in[3],
      (const float*)d_in[4], (const float*)d_in[5],
      (const float*)d_in[6], (const float*)d_in[7], ws);
  k_stats<<<dim3(72,8), 512, 0, stream>>>(ws);
  k_attn <<<dim3(72,8), 512, 0, stream>>>(ws);
  k_out  <<<dim3(36,2,8), 256, 0, stream>>>(
      ws,
      (const float*)d_in[8],  (const float*)d_in[9],
      (const float*)d_in[10], (const float*)d_in[11],
      (const float*)d_in[12], (const float*)d_in[13],
      (const float*)d_in[14], (const float*)d_in[15],
      (float*)d_out);
}

// Round 12
// 261.438 us; speedup vs baseline: 1.1218x; 1.1218x over previous
//
#include <hip/hip_runtime.h>

typedef unsigned short u16;
typedef __bf16 bf16_t;
typedef bf16_t bf16x8 __attribute__((ext_vector_type(8)));
typedef float f32x4 __attribute__((ext_vector_type(4)));

#define B_   8
#define CH   64
#define HW   2304
#define L2E  1.4426950408889634f

// ---- workspace byte offsets ----
#define OFF_XLC   0u          // bf16 [8][64][2304] channel-major
#define OFF_XRC   2359296u
#define OFF_XLT   4718592u    // bf16 [8][2304][64] position-major
#define OFF_XRT   7077888u
#define OFF_B1    9437184u    // f32  [8][64][2304]
#define OFF_B2    14155776u
#define OFF_RS2   18874368u   // f32  [8][2304]  1/S2[n]
// total 18948096 bytes

__device__ __forceinline__ float bf2f(u16 u){
  union { unsigned int i; float f; } v; v.i = ((unsigned int)u) << 16; return v.f;
}
__device__ __forceinline__ u16 f2bf(float f){
  union { float f; unsigned int i; } v; v.f = f;
  unsigned int r = v.i + 0x7FFFu + ((v.i >> 16) & 1u);
  return (u16)(r >> 16);
}

// ---------------- K1: xL/xR = W[64x128] @ concat(x_h,x_l) + b ----------------
// grid (9, 4, 16): p = bx*256+t, o0 = by*16, (b,side) = (bz>>1, bz&1)
__global__ __launch_bounds__(256) void k_proj(
    const float* xlh, const float* xll, const float* xrh, const float* xrl,
    const float* wLl, const float* bLl, const float* wRr, const float* bRr,
    char* ws)
{
  int p  = blockIdx.x*256 + threadIdx.x;
  int o0 = blockIdx.y*16;
  int b  = blockIdx.z >> 1, side = blockIdx.z & 1;
  const float* xh = (side ? xrh : xlh) + (size_t)b*CH*HW;
  const float* xl = (side ? xrl : xll) + (size_t)b*CH*HW;
  const float* w  = (side ? wRr : wLl);
  const float* bi = (side ? bRr : bLl);

  float acc[16];
  #pragma unroll
  for (int j=0;j<16;j++) acc[j] = bi[o0+j];
  for (int c=0;c<64;c++){
    float xv = xh[(size_t)c*HW + p];
    #pragma unroll
    for (int j=0;j<16;j++) acc[j] = fmaf(w[(size_t)(o0+j)*128 + c], xv, acc[j]);
  }
  for (int c=0;c<64;c++){
    float xv = xl[(size_t)c*HW + p];
    #pragma unroll
    for (int j=0;j<16;j++) acc[j] = fmaf(w[(size_t)(o0+j)*128 + 64 + c], xv, acc[j]);
  }
  u16* xc = (u16*)(ws + (side ? OFF_XRC : OFF_XLC)) + (size_t)b*CH*HW;
  u16* xt = (u16*)(ws + (side ? OFF_XRT : OFF_XLT)) + (size_t)b*HW*CH;
  unsigned int pk[8];
  #pragma unroll
  for (int j=0;j<8;j++){
    unsigned int lo16 = f2bf(acc[2*j]);
    unsigned int hi16 = f2bf(acc[2*j+1]);
    pk[j] = lo16 | (hi16 << 16);
    xc[(size_t)(o0+2*j  )*HW + p] = (u16)lo16;
    xc[(size_t)(o0+2*j+1)*HW + p] = (u16)hi16;
  }
  uint4* dst = (uint4*)&xt[(size_t)p*CH + o0];
  dst[0] = make_uint4(pk[0],pk[1],pk[2],pk[3]);
  dst[1] = make_uint4(pk[4],pk[5],pk[6],pk[7]);
}

// ---------------- K2: 1/S2[n]; 16 rows/block, 4 waves x m-quarter, 2 j-streams ----------------
// grid (144, 8)
__global__ __launch_bounds__(256, 4) void k_stats(char* ws)
{
  __shared__ float part[4][4][4];
  int b = blockIdx.y;
  const u16* X = (const u16*)(ws + OFF_XLT) + (size_t)b*HW*CH;   // rows n
  const u16* Y = (const u16*)(ws + OFF_XRT) + (size_t)b*HW*CH;   // reduce over m
  float* out = (float*)(ws + OFF_RS2) + b*HW;

  int lane = threadIdx.x & 63;
  int wv   = __builtin_amdgcn_readfirstlane(threadIdx.x >> 6);
  int lo = lane & 15, g = lane >> 4;
  int r0 = blockIdx.x*16;

  bf16x8 a0 = *(const bf16x8*)&X[(size_t)(r0+lo)*CH + 8*g];
  bf16x8 a1 = *(const bf16x8*)&X[(size_t)(r0+lo)*CH + 32 + 8*g];

  float sP[4] = {0.f,0.f,0.f,0.f};
  float sQ[4] = {0.f,0.f,0.f,0.f};
  int jb = wv * 576;

  bf16x8 bP0 = *(const bf16x8*)&Y[(size_t)(jb+lo)*CH + 8*g];
  bf16x8 bP1 = *(const bf16x8*)&Y[(size_t)(jb+lo)*CH + 32 + 8*g];
  bf16x8 bQ0 = *(const bf16x8*)&Y[(size_t)(jb+288+lo)*CH + 8*g];
  bf16x8 bQ1 = *(const bf16x8*)&Y[(size_t)(jb+288+lo)*CH + 32 + 8*g];
  for (int i = 0; i < 18; ++i){
    int jn = jb + ((i+1 < 18) ? (i+1)*16 : 0);
    bf16x8 nP0 = *(const bf16x8*)&Y[(size_t)(jn+lo)*CH + 8*g];
    bf16x8 nP1 = *(const bf16x8*)&Y[(size_t)(jn+lo)*CH + 32 + 8*g];
    bf16x8 nQ0 = *(const bf16x8*)&Y[(size_t)(jn+288+lo)*CH + 8*g];
    bf16x8 nQ1 = *(const bf16x8*)&Y[(size_t)(jn+288+lo)*CH + 32 + 8*g];
    f32x4 z4 = {0.f,0.f,0.f,0.f};
    f32x4 dP = __builtin_amdgcn_mfma_f32_16x16x32_bf16(a0, bP0, z4, 0,0,0);
    dP = __builtin_amdgcn_mfma_f32_16x16x32_bf16(a1, bP1, dP, 0,0,0);
    f32x4 dQ = __builtin_amdgcn_mfma_f32_16x16x32_bf16(a0, bQ0, z4, 0,0,0);
    dQ = __builtin_amdgcn_mfma_f32_16x16x32_bf16(a1, bQ1, dQ, 0,0,0);
    #pragma unroll
    for (int r=0;r<4;r++){ sP[r] += exp2f(dP[r]*L2E); sQ[r] += exp2f(dQ[r]*L2E); }
    bP0 = nP0; bP1 = nP1; bQ0 = nQ0; bQ1 = nQ1;
  }
  float s[4];
  #pragma unroll
  for (int r=0;r<4;r++) s[r] = sP[r] + sQ[r];
  #pragma unroll
  for (int mask = 1; mask < 16; mask <<= 1){
    #pragma unroll
    for (int r=0;r<4;r++) s[r] += __shfl_xor(s[r], mask, 64);
  }
  if (lo == 0){
    #pragma unroll
    for (int r=0;r<4;r++) part[wv][g][r] = s[r];
  }
  __syncthreads();
  if (threadIdx.x < 16){
    int t = threadIdx.x;
    float sum = part[0][t>>2][t&3] + part[1][t>>2][t&3]
              + part[2][t>>2][t&3] + part[3][t>>2][t&3];
    out[r0 + t] = 1.0f / sum;
  }
}

// ---------------- K3 helpers (16-m variant) ----------------
__device__ __forceinline__ void attn_compute(
    const bf16x8& fa00, const bf16x8& fa01, const bf16x8& fa10, const bf16x8& fa11,
    const bf16x8& bL0, const bf16x8& bL1, const bf16x8& bL2, const bf16x8& bL3,
    const bf16x8& bR0, const bf16x8& bR1, const bf16x8& bR2, const bf16x8& bR3,
    const f32x4& r20, const f32x4& r21,
    const bf16x8& fm0, const bf16x8& fm1,
    f32x4 acc1[4], f32x4 acc2[4], float& s1)
{
  f32x4 z4 = {0.f,0.f,0.f,0.f};
  f32x4 d0 = __builtin_amdgcn_mfma_f32_16x16x32_bf16(fa00, fm0, z4, 0,0,0);
  d0 = __builtin_amdgcn_mfma_f32_16x16x32_bf16(fa01, fm1, d0, 0,0,0);
  f32x4 d1 = __builtin_amdgcn_mfma_f32_16x16x32_bf16(fa10, fm0, z4, 0,0,0);
  d1 = __builtin_amdgcn_mfma_f32_16x16x32_bf16(fa11, fm1, d1, 0,0,0);

  bf16x8 pa1, pa2;
  #pragma unroll
  for (int r=0;r<4;r++){
    float e0 = exp2f(d0[r]*L2E);
    float e1 = exp2f(d1[r]*L2E);
    s1 += e0 + e1;
    pa1[r]   = (bf16_t)e0;            // unnormalized; 1/S1 applied at writeout
    pa1[r+4] = (bf16_t)e1;
    pa2[r]   = (bf16_t)(e0 * r20[r]); // 1/S2[n] applied per-lane
    pa2[r+4] = (bf16_t)(e1 * r21[r]);
  }
  acc1[0] = __builtin_amdgcn_mfma_f32_16x16x32_bf16(pa1, bL0, acc1[0], 0,0,0);
  acc1[1] = __builtin_amdgcn_mfma_f32_16x16x32_bf16(pa1, bL1, acc1[1], 0,0,0);
  acc1[2] = __builtin_amdgcn_mfma_f32_16x16x32_bf16(pa1, bL2, acc1[2], 0,0,0);
  acc1[3] = __builtin_amdgcn_mfma_f32_16x16x32_bf16(pa1, bL3, acc1[3], 0,0,0);
  acc2[0] = __builtin_amdgcn_mfma_f32_16x16x32_bf16(pa2, bR0, acc2[0], 0,0,0);
  acc2[1] = __builtin_amdgcn_mfma_f32_16x16x32_bf16(pa2, bR1, acc2[1], 0,0,0);
  acc2[2] = __builtin_amdgcn_mfma_f32_16x16x32_bf16(pa2, bR2, acc2[2], 0,0,0);
  acc2[3] = __builtin_amdgcn_mfma_f32_16x16x32_bf16(pa2, bR3, acc2[3], 0,0,0);
}

#define ATTN_LOAD(S, n0) \
  fa00##S = *(const bf16x8*)&XLt[(size_t)((n0)+pr  )*CH +      8*g]; \
  fa01##S = *(const bf16x8*)&XLt[(size_t)((n0)+pr  )*CH + 32 + 8*g]; \
  fa10##S = *(const bf16x8*)&XLt[(size_t)((n0)+pr+4)*CH +      8*g]; \
  fa11##S = *(const bf16x8*)&XLt[(size_t)((n0)+pr+4)*CH + 32 + 8*g]; \
  bL0##S = *(const bf16x8*)&XLc[(size_t)( 0+lo)*HW + (n0) + 8*g];    \
  bL1##S = *(const bf16x8*)&XLc[(size_t)(16+lo)*HW + (n0) + 8*g];    \
  bL2##S = *(const bf16x8*)&XLc[(size_t)(32+lo)*HW + (n0) + 8*g];    \
  bL3##S = *(const bf16x8*)&XLc[(size_t)(48+lo)*HW + (n0) + 8*g];    \
  bR0##S = *(const bf16x8*)&XRc[(size_t)( 0+lo)*HW + (n0) + 8*g];    \
  bR1##S = *(const bf16x8*)&XRc[(size_t)(16+lo)*HW + (n0) + 8*g];    \
  bR2##S = *(const bf16x8*)&XRc[(size_t)(32+lo)*HW + (n0) + 8*g];    \
  bR3##S = *(const bf16x8*)&XRc[(size_t)(48+lo)*HW + (n0) + 8*g];    \
  r20##S = *(const f32x4*)&rs2[(n0) + 8*g];                          \
  r21##S = *(const f32x4*)&rs2[(n0) + 8*g + 4];

// ---------------- K3: fused aff->P -> b1^T/b2^T; 16 m/block, 4 waves x n-quarter ----------------
// grid (144, 8): wave wv covers n in [wv*576, wv*576+576) = 18 steps of 32
__global__ __launch_bounds__(256, 4) void k_attn(char* ws)
{
  __shared__ float red[4][64][17];
  __shared__ float s1part[4][16];
  __shared__ float rs1inv[16];
  int b    = blockIdx.y;
  int lane = threadIdx.x & 63;
  int wv   = __builtin_amdgcn_readfirstlane(threadIdx.x >> 6);
  int lo = lane & 15, g = lane >> 4;
  int m0 = blockIdx.x * 16;

  const u16* XLt = (const u16*)(ws + OFF_XLT) + (size_t)b*HW*CH;
  const u16* XRt = (const u16*)(ws + OFF_XRT) + (size_t)b*HW*CH;
  const u16* XLc = (const u16*)(ws + OFF_XLC) + (size_t)b*CH*HW;
  const u16* XRc = (const u16*)(ws + OFF_XRC) + (size_t)b*CH*HW;
  const float* rs2 = (const float*)(ws + OFF_RS2) + b*HW;

  bf16x8 fm0 = *(const bf16x8*)&XRt[(size_t)(m0+lo)*CH + 8*g];
  bf16x8 fm1 = *(const bf16x8*)&XRt[(size_t)(m0+lo)*CH + 32 + 8*g];

  int pr = ((lo >> 2) << 3) + (lo & 3);

  f32x4 acc1[4], acc2[4];
  #pragma unroll
  for (int ct=0;ct<4;ct++){
    f32x4 z4 = {0.f,0.f,0.f,0.f};
    acc1[ct]=z4; acc2[ct]=z4;
  }
  float s1 = 0.f;

  int nbeg = wv * 576;
  bf16x8 fa00X, fa01X, fa10X, fa11X, bL0X, bL1X, bL2X, bL3X, bR0X, bR1X, bR2X, bR3X;
  bf16x8 fa00Y, fa01Y, fa10Y, fa11Y, bL0Y, bL1Y, bL2Y, bL3Y, bR0Y, bR1Y, bR2Y, bR3Y;
  f32x4 r20X, r21X, r20Y, r21Y;

  ATTN_LOAD(X, nbeg)
  for (int s = 0; s < 18; s += 2){
    ATTN_LOAD(Y, nbeg + (s+1)*32)
    attn_compute(fa00X,fa01X,fa10X,fa11X, bL0X,bL1X,bL2X,bL3X, bR0X,bR1X,bR2X,bR3X,
                 r20X,r21X, fm0,fm1, acc1,acc2, s1);
    int n2 = nbeg + ((s+2 < 18) ? (s+2)*32 : 0);
    ATTN_LOAD(X, n2)
    attn_compute(fa00Y,fa01Y,fa10Y,fa11Y, bL0Y,bL1Y,bL2Y,bL3Y, bR0Y,bR1Y,bR2Y,bR3Y,
                 r20Y,r21Y, fm0,fm1, acc1,acc2, s1);
  }

  // ---- S1 block reduction (S1[m0+lo] partial per lane; sum over g then waves) ----
  s1 += __shfl_xor(s1, 16, 64);
  s1 += __shfl_xor(s1, 32, 64);
  if (lane < 16) s1part[wv][lane] = s1;
  __syncthreads();
  if (threadIdx.x < 16){
    int t = threadIdx.x;
    float s = s1part[0][t] + s1part[1][t] + s1part[2][t] + s1part[3][t];
    rs1inv[t] = 1.0f / s;
  }
  __syncthreads();

  float* B1 = (float*)(ws + OFF_B1) + (size_t)b*CH*HW;
  float* B2 = (float*)(ws + OFF_B2) + (size_t)b*CH*HW;
  int rl = threadIdx.x & 63;
  int rv = threadIdx.x >> 6;          // 0..3

  // phase 1: acc1 -> B1 (scaled by rs1inv)
  #pragma unroll
  for (int v=0; v<16; ++v) red[wv][lane][v] = acc1[v>>2][v&3];
  __syncthreads();
  #pragma unroll
  for (int k=0;k<4;k++){
    int v = rv + 4*k;
    float s = red[0][rl][v] + red[1][rl][v] + red[2][rl][v] + red[3][rl][v];
    int midx = ((rl>>4)<<2) + (v&3);
    int c = ((v>>2)<<4) + (rl & 15);
    B1[(size_t)c*HW + m0 + midx] = s * rs1inv[midx];
  }
  __syncthreads();
  // phase 2: acc2 -> B2
  #pragma unroll
  for (int v=0; v<16; ++v) red[wv][lane][v] = acc2[v>>2][v&3];
  __syncthreads();
  #pragma unroll
  for (int k=0;k<4;k++){
    int v = rv + 4*k;
    float s = red[0][rl][v] + red[1][rl][v] + red[2][rl][v] + red[3][rl][v];
    int midx = ((rl>>4)<<2) + (v&3);
    int c = ((v>>2)<<4) + (rl & 15);
    B2[(size_t)c*HW + m0 + midx] = s;
  }
}

// ---------------- K4: gate + output convs (raw f32 weights), f32 OUTPUT ----------------
// grid (36, 2, 8): p-tile of 64, side, batch
__global__ __launch_bounds__(256) void k_out(
    char* ws,
    const float* gwL, const float* gbL, const float* gwR, const float* gbR,
    const float* wLo, const float* bLoi, const float* wRo, const float* bRoi,
    float* out)
{
  __shared__ float xT[64][64];
  __shared__ float bT[64][64];
  __shared__ float gpart[4][64];
  __shared__ float gLds[64];
  int t = threadIdx.x;
  int p0 = blockIdx.x*64;
  int side = blockIdx.y;
  int b = blockIdx.z;
  const float* braw = (const float*)(ws + (side ? OFF_B2 : OFF_B1)) + (size_t)b*CH*HW;
  const u16*   xc   = (const u16*)(ws + (side ? OFF_XRC : OFF_XLC)) + (size_t)b*CH*HW;
  const float* w    = side ? wRo : wLo;
  const float* gw   = side ? gwR : gwL;
  float        gb   = side ? gbR[0] : gbL[0];
  const float* bias = side ? bRoi : bLoi;

  #pragma unroll
  for (int i=0;i<16;i++){
    int flat = i*256 + t;
    int c = flat >> 6, pl = flat & 63;
    bT[c][pl] = braw[(size_t)c*HW + p0 + pl];
    xT[c][pl] = bf2f(xc[(size_t)c*HW + p0 + pl]);
  }
  __syncthreads();
  {
    int q = t >> 6, pl = t & 63;
    float a = 0.f;
    #pragma unroll
    for (int c = 0; c < 16; c++) a = fmaf(gw[16*q + c], bT[16*q + c][pl], a);
    gpart[q][pl] = a;
  }
  __syncthreads();
  if (t < 64){
    float x = gpart[0][t]+gpart[1][t]+gpart[2][t]+gpart[3][t] + gb;
    gLds[t] = 1.0f/(1.0f + exp2f(-x*L2E));    // sigmoid
  }
  __syncthreads();
  #pragma unroll
  for (int i=0;i<16;i++){
    int flat = i*256 + t;
    int c = flat >> 6, pl = flat & 63;
    bT[c][pl] *= gLds[pl];
  }
  __syncthreads();
  int wv = t >> 6;
  int lane = t & 63;
  float* outp = out + ((size_t)side*B_ + b)*CH*HW;
  for (int oi=0; oi<16; oi++){
    int o = wv*16 + oi;
    float a = bias[o];
    #pragma unroll 8
    for (int c=0;c<64;c++){
      a = fmaf(w[o*128 + c],      xT[c][lane], a);
      a = fmaf(w[o*128 + 64 + c], bT[c][lane], a);
    }
    outp[(size_t)o*HW + p0 + lane] = a;
  }
}

extern "C" void kernel_launch(void* const* d_in, const int* in_sizes, int n_in,
                              void* d_out, int out_size, void* d_ws, size_t ws_size,
                              hipStream_t stream)
{
  char* ws = (char*)d_ws;
  k_proj <<<dim3(9,4,16), 256, 0, stream>>>(
      (const float*)d_in[0], (const float*)d_in[1],
      (const float*)d_in[2], (const float*)d_in[3],
      (const float*)d_in[4], (const float*)d_in[5],
      (const float*)d_in[6], (const float*)d_in[7], ws);
  k_stats<<<dim3(144,8), 256, 0, stream>>>(ws);
  k_attn <<<dim3(144,8), 256, 0, stream>>>(ws);
  k_out  <<<dim3(36,2,8), 256, 0, stream>>>(
      ws,
      (const float*)d_in[8],  (const float*)d_in[9],
      (const float*)d_in[10], (const float*)d_in[11],
      (const float*)d_in[12], (const float*)d_in[13],
      (const float*)d_in[14], (const float*)d_in[15],
      (float*)d_out);
}

// Round 13
// 220.337 us; speedup vs baseline: 1.3310x; 1.1865x over previous
//
#include <hip/hip_runtime.h>

typedef unsigned short u16;
typedef __bf16 bf16_t;
typedef bf16_t bf16x8 __attribute__((ext_vector_type(8)));
typedef float f32x4 __attribute__((ext_vector_type(4)));

#define B_   8
#define CH   64
#define HW   2304
#define L2E  1.4426950408889634f

// ---- workspace byte offsets ----
#define OFF_XLC   0u          // bf16 [8][64][2304] channel-major
#define OFF_XRC   2359296u
#define OFF_XLT   4718592u    // bf16 [8][2304][64] position-major
#define OFF_XRT   7077888u
#define OFF_B1    9437184u    // f32  [8][64][2304]
#define OFF_B2    14155776u
#define OFF_RS2   18874368u   // f32  [8][2304]  1/S2[n]
// total 18948096 bytes

__device__ __forceinline__ float bf2f(u16 u){
  union { unsigned int i; float f; } v; v.i = ((unsigned int)u) << 16; return v.f;
}
__device__ __forceinline__ u16 f2bf(float f){
  union { float f; unsigned int i; } v; v.f = f;
  unsigned int r = v.i + 0x7FFFu + ((v.i >> 16) & 1u);
  return (u16)(r >> 16);
}

// ---------------- K1: xL/xR = W[64x128] @ concat(x_h,x_l) + b ----------------
// 1-D grid 288: b = bid%8 (XCD affinity); q = bid/8: o0=(q&1)*32, side=(q>>1)&1, px=q>>2
__global__ __launch_bounds__(256) void k_proj(
    const float* xlh, const float* xll, const float* xrh, const float* xrl,
    const float* wLl, const float* bLl, const float* wRr, const float* bRr,
    char* ws)
{
  int bid = blockIdx.x;
  int b   = bid & 7;
  int q   = bid >> 3;
  int o0  = (q & 1) * 32;
  int side= (q >> 1) & 1;
  int p   = (q >> 2) * 256 + threadIdx.x;
  const float* xh = (side ? xrh : xlh) + (size_t)b*CH*HW;
  const float* xl = (side ? xrl : xll) + (size_t)b*CH*HW;
  const float* w  = (side ? wRr : wLl);
  const float* bi = (side ? bRr : bLl);

  float acc[32];
  #pragma unroll
  for (int j=0;j<32;j++) acc[j] = bi[o0+j];
  for (int c=0;c<64;c++){
    float xv = xh[(size_t)c*HW + p];
    #pragma unroll
    for (int j=0;j<32;j++) acc[j] = fmaf(w[(size_t)(o0+j)*128 + c], xv, acc[j]);
  }
  for (int c=0;c<64;c++){
    float xv = xl[(size_t)c*HW + p];
    #pragma unroll
    for (int j=0;j<32;j++) acc[j] = fmaf(w[(size_t)(o0+j)*128 + 64 + c], xv, acc[j]);
  }
  u16* xc = (u16*)(ws + (side ? OFF_XRC : OFF_XLC)) + (size_t)b*CH*HW;
  u16* xt = (u16*)(ws + (side ? OFF_XRT : OFF_XLT)) + (size_t)b*HW*CH;
  unsigned int pk[16];
  #pragma unroll
  for (int j=0;j<16;j++){
    unsigned int lo16 = f2bf(acc[2*j]);
    unsigned int hi16 = f2bf(acc[2*j+1]);
    pk[j] = lo16 | (hi16 << 16);
    xc[(size_t)(o0+2*j  )*HW + p] = (u16)lo16;
    xc[(size_t)(o0+2*j+1)*HW + p] = (u16)hi16;
  }
  uint4* dst = (uint4*)&xt[(size_t)p*CH + o0];
  dst[0] = make_uint4(pk[0],pk[1],pk[2],pk[3]);
  dst[1] = make_uint4(pk[4],pk[5],pk[6],pk[7]);
  dst[2] = make_uint4(pk[8],pk[9],pk[10],pk[11]);
  dst[3] = make_uint4(pk[12],pk[13],pk[14],pk[15]);
}

// ---------------- K2: 1/S2[n]; 16 rows/block, 4 waves x m-quarter, 2 j-streams ----------------
// 1-D grid 1152: b = bid%8 (XCD affinity); r0 = (bid/8)*16
__global__ __launch_bounds__(256, 4) void k_stats(char* ws)
{
  __shared__ float part[4][4][4];
  int bid = blockIdx.x;
  int b   = bid & 7;
  int r0  = (bid >> 3) * 16;
  const u16* X = (const u16*)(ws + OFF_XLT) + (size_t)b*HW*CH;   // rows n
  const u16* Y = (const u16*)(ws + OFF_XRT) + (size_t)b*HW*CH;   // reduce over m
  float* out = (float*)(ws + OFF_RS2) + b*HW;

  int lane = threadIdx.x & 63;
  int wv   = __builtin_amdgcn_readfirstlane(threadIdx.x >> 6);
  int lo = lane & 15, g = lane >> 4;

  bf16x8 a0 = *(const bf16x8*)&X[(size_t)(r0+lo)*CH + 8*g];
  bf16x8 a1 = *(const bf16x8*)&X[(size_t)(r0+lo)*CH + 32 + 8*g];

  float sP[4] = {0.f,0.f,0.f,0.f};
  float sQ[4] = {0.f,0.f,0.f,0.f};
  int jb = wv * 576;

  bf16x8 bP0 = *(const bf16x8*)&Y[(size_t)(jb+lo)*CH + 8*g];
  bf16x8 bP1 = *(const bf16x8*)&Y[(size_t)(jb+lo)*CH + 32 + 8*g];
  bf16x8 bQ0 = *(const bf16x8*)&Y[(size_t)(jb+288+lo)*CH + 8*g];
  bf16x8 bQ1 = *(const bf16x8*)&Y[(size_t)(jb+288+lo)*CH + 32 + 8*g];
  for (int i = 0; i < 18; ++i){
    int jn = jb + ((i+1 < 18) ? (i+1)*16 : 0);
    bf16x8 nP0 = *(const bf16x8*)&Y[(size_t)(jn+lo)*CH + 8*g];
    bf16x8 nP1 = *(const bf16x8*)&Y[(size_t)(jn+lo)*CH + 32 + 8*g];
    bf16x8 nQ0 = *(const bf16x8*)&Y[(size_t)(jn+288+lo)*CH + 8*g];
    bf16x8 nQ1 = *(const bf16x8*)&Y[(size_t)(jn+288+lo)*CH + 32 + 8*g];
    f32x4 z4 = {0.f,0.f,0.f,0.f};
    f32x4 dP = __builtin_amdgcn_mfma_f32_16x16x32_bf16(a0, bP0, z4, 0,0,0);
    dP = __builtin_amdgcn_mfma_f32_16x16x32_bf16(a1, bP1, dP, 0,0,0);
    f32x4 dQ = __builtin_amdgcn_mfma_f32_16x16x32_bf16(a0, bQ0, z4, 0,0,0);
    dQ = __builtin_amdgcn_mfma_f32_16x16x32_bf16(a1, bQ1, dQ, 0,0,0);
    #pragma unroll
    for (int r=0;r<4;r++){ sP[r] += exp2f(dP[r]*L2E); sQ[r] += exp2f(dQ[r]*L2E); }
    bP0 = nP0; bP1 = nP1; bQ0 = nQ0; bQ1 = nQ1;
  }
  float s[4];
  #pragma unroll
  for (int r=0;r<4;r++) s[r] = sP[r] + sQ[r];
  #pragma unroll
  for (int mask = 1; mask < 16; mask <<= 1){
    #pragma unroll
    for (int r=0;r<4;r++) s[r] += __shfl_xor(s[r], mask, 64);
  }
  if (lo == 0){
    #pragma unroll
    for (int r=0;r<4;r++) part[wv][g][r] = s[r];
  }
  __syncthreads();
  if (threadIdx.x < 16){
    int t = threadIdx.x;
    float sum = part[0][t>>2][t&3] + part[1][t>>2][t&3]
              + part[2][t>>2][t&3] + part[3][t>>2][t&3];
    out[r0 + t] = 1.0f / sum;
  }
}

// ---------------- K3 helpers (32-m, r9 structure) ----------------
__device__ __forceinline__ void attn_compute(
    const bf16x8& fa00, const bf16x8& fa01, const bf16x8& fa10, const bf16x8& fa11,
    const bf16x8& bL0, const bf16x8& bL1, const bf16x8& bL2, const bf16x8& bL3,
    const bf16x8& bR0, const bf16x8& bR1, const bf16x8& bR2, const bf16x8& bR3,
    const f32x4& r20, const f32x4& r21,
    const bf16x8& fmA0, const bf16x8& fmA1, const bf16x8& fmB0, const bf16x8& fmB1,
    f32x4 acc1A[4], f32x4 acc2A[4], f32x4 acc1B[4], f32x4 acc2B[4],
    float& s1A, float& s1B)
{
  f32x4 z4 = {0.f,0.f,0.f,0.f};
  f32x4 d0A = __builtin_amdgcn_mfma_f32_16x16x32_bf16(fa00, fmA0, z4, 0,0,0);
  d0A = __builtin_amdgcn_mfma_f32_16x16x32_bf16(fa01, fmA1, d0A, 0,0,0);
  f32x4 d1A = __builtin_amdgcn_mfma_f32_16x16x32_bf16(fa10, fmA0, z4, 0,0,0);
  d1A = __builtin_amdgcn_mfma_f32_16x16x32_bf16(fa11, fmA1, d1A, 0,0,0);
  f32x4 d0B = __builtin_amdgcn_mfma_f32_16x16x32_bf16(fa00, fmB0, z4, 0,0,0);
  d0B = __builtin_amdgcn_mfma_f32_16x16x32_bf16(fa01, fmB1, d0B, 0,0,0);
  f32x4 d1B = __builtin_amdgcn_mfma_f32_16x16x32_bf16(fa10, fmB0, z4, 0,0,0);
  d1B = __builtin_amdgcn_mfma_f32_16x16x32_bf16(fa11, fmB1, d1B, 0,0,0);

  bf16x8 pa1A, pa2A, pa1B, pa2B;
  #pragma unroll
  for (int r=0;r<4;r++){
    float e0 = exp2f(d0A[r]*L2E);
    float e1 = exp2f(d1A[r]*L2E);
    s1A += e0 + e1;
    pa1A[r]   = (bf16_t)e0;            // unnormalized; 1/S1 applied at writeout
    pa1A[r+4] = (bf16_t)e1;
    pa2A[r]   = (bf16_t)(e0 * r20[r]); // 1/S2[n] applied per-lane
    pa2A[r+4] = (bf16_t)(e1 * r21[r]);
    float f0 = exp2f(d0B[r]*L2E);
    float f1 = exp2f(d1B[r]*L2E);
    s1B += f0 + f1;
    pa1B[r]   = (bf16_t)f0;
    pa1B[r+4] = (bf16_t)f1;
    pa2B[r]   = (bf16_t)(f0 * r20[r]);
    pa2B[r+4] = (bf16_t)(f1 * r21[r]);
  }
  acc1A[0] = __builtin_amdgcn_mfma_f32_16x16x32_bf16(pa1A, bL0, acc1A[0], 0,0,0);
  acc1A[1] = __builtin_amdgcn_mfma_f32_16x16x32_bf16(pa1A, bL1, acc1A[1], 0,0,0);
  acc1A[2] = __builtin_amdgcn_mfma_f32_16x16x32_bf16(pa1A, bL2, acc1A[2], 0,0,0);
  acc1A[3] = __builtin_amdgcn_mfma_f32_16x16x32_bf16(pa1A, bL3, acc1A[3], 0,0,0);
  acc2A[0] = __builtin_amdgcn_mfma_f32_16x16x32_bf16(pa2A, bR0, acc2A[0], 0,0,0);
  acc2A[1] = __builtin_amdgcn_mfma_f32_16x16x32_bf16(pa2A, bR1, acc2A[1], 0,0,0);
  acc2A[2] = __builtin_amdgcn_mfma_f32_16x16x32_bf16(pa2A, bR2, acc2A[2], 0,0,0);
  acc2A[3] = __builtin_amdgcn_mfma_f32_16x16x32_bf16(pa2A, bR3, acc2A[3], 0,0,0);
  acc1B[0] = __builtin_amdgcn_mfma_f32_16x16x32_bf16(pa1B, bL0, acc1B[0], 0,0,0);
  acc1B[1] = __builtin_amdgcn_mfma_f32_16x16x32_bf16(pa1B, bL1, acc1B[1], 0,0,0);
  acc1B[2] = __builtin_amdgcn_mfma_f32_16x16x32_bf16(pa1B, bL2, acc1B[2], 0,0,0);
  acc1B[3] = __builtin_amdgcn_mfma_f32_16x16x32_bf16(pa1B, bL3, acc1B[3], 0,0,0);
  acc2B[0] = __builtin_amdgcn_mfma_f32_16x16x32_bf16(pa2B, bR0, acc2B[0], 0,0,0);
  acc2B[1] = __builtin_amdgcn_mfma_f32_16x16x32_bf16(pa2B, bR1, acc2B[1], 0,0,0);
  acc2B[2] = __builtin_amdgcn_mfma_f32_16x16x32_bf16(pa2B, bR2, acc2B[2], 0,0,0);
  acc2B[3] = __builtin_amdgcn_mfma_f32_16x16x32_bf16(pa2B, bR3, acc2B[3], 0,0,0);
}

#define ATTN_LOAD(S, n0) \
  fa00##S = *(const bf16x8*)&XLt[(size_t)((n0)+pr  )*CH +      8*g]; \
  fa01##S = *(const bf16x8*)&XLt[(size_t)((n0)+pr  )*CH + 32 + 8*g]; \
  fa10##S = *(const bf16x8*)&XLt[(size_t)((n0)+pr+4)*CH +      8*g]; \
  fa11##S = *(const bf16x8*)&XLt[(size_t)((n0)+pr+4)*CH + 32 + 8*g]; \
  bL0##S = *(const bf16x8*)&XLc[(size_t)( 0+lo)*HW + (n0) + 8*g];    \
  bL1##S = *(const bf16x8*)&XLc[(size_t)(16+lo)*HW + (n0) + 8*g];    \
  bL2##S = *(const bf16x8*)&XLc[(size_t)(32+lo)*HW + (n0) + 8*g];    \
  bL3##S = *(const bf16x8*)&XLc[(size_t)(48+lo)*HW + (n0) + 8*g];    \
  bR0##S = *(const bf16x8*)&XRc[(size_t)( 0+lo)*HW + (n0) + 8*g];    \
  bR1##S = *(const bf16x8*)&XRc[(size_t)(16+lo)*HW + (n0) + 8*g];    \
  bR2##S = *(const bf16x8*)&XRc[(size_t)(32+lo)*HW + (n0) + 8*g];    \
  bR3##S = *(const bf16x8*)&XRc[(size_t)(48+lo)*HW + (n0) + 8*g];    \
  r20##S = *(const f32x4*)&rs2[(n0) + 8*g];                          \
  r21##S = *(const f32x4*)&rs2[(n0) + 8*g + 4];

// ---------------- K3: fused aff->P -> b1^T/b2^T; 32 m/block, 4 waves x n-quarter ----------------
// 1-D grid 576: b = bid%8 (XCD affinity); m0 = (bid/8)*32
__global__ __launch_bounds__(256, 2) void k_attn(char* ws)
{
  __shared__ float red[4][64][17];
  __shared__ float s1part[4][32];
  __shared__ float rs1inv[32];
  int bid  = blockIdx.x;
  int b    = bid & 7;
  int m0   = (bid >> 3) * 32;
  int lane = threadIdx.x & 63;
  int wv   = __builtin_amdgcn_readfirstlane(threadIdx.x >> 6);
  int lo = lane & 15, g = lane >> 4;

  const u16* XLt = (const u16*)(ws + OFF_XLT) + (size_t)b*HW*CH;
  const u16* XRt = (const u16*)(ws + OFF_XRT) + (size_t)b*HW*CH;
  const u16* XLc = (const u16*)(ws + OFF_XLC) + (size_t)b*CH*HW;
  const u16* XRc = (const u16*)(ws + OFF_XRC) + (size_t)b*CH*HW;
  const float* rs2 = (const float*)(ws + OFF_RS2) + b*HW;

  bf16x8 fmA0 = *(const bf16x8*)&XRt[(size_t)(m0+lo)*CH + 8*g];
  bf16x8 fmA1 = *(const bf16x8*)&XRt[(size_t)(m0+lo)*CH + 32 + 8*g];
  bf16x8 fmB0 = *(const bf16x8*)&XRt[(size_t)(m0+16+lo)*CH + 8*g];
  bf16x8 fmB1 = *(const bf16x8*)&XRt[(size_t)(m0+16+lo)*CH + 32 + 8*g];

  int pr = ((lo >> 2) << 3) + (lo & 3);

  f32x4 acc1A[4], acc2A[4], acc1B[4], acc2B[4];
  #pragma unroll
  for (int ct=0;ct<4;ct++){
    f32x4 z4 = {0.f,0.f,0.f,0.f};
    acc1A[ct]=z4; acc2A[ct]=z4; acc1B[ct]=z4; acc2B[ct]=z4;
  }
  float s1A = 0.f, s1B = 0.f;

  int nbeg = wv * 576;
  bf16x8 fa00X, fa01X, fa10X, fa11X, bL0X, bL1X, bL2X, bL3X, bR0X, bR1X, bR2X, bR3X;
  bf16x8 fa00Y, fa01Y, fa10Y, fa11Y, bL0Y, bL1Y, bL2Y, bL3Y, bR0Y, bR1Y, bR2Y, bR3Y;
  f32x4 r20X, r21X, r20Y, r21Y;

  ATTN_LOAD(X, nbeg)
  for (int s = 0; s < 18; s += 2){
    ATTN_LOAD(Y, nbeg + (s+1)*32)
    attn_compute(fa00X,fa01X,fa10X,fa11X, bL0X,bL1X,bL2X,bL3X, bR0X,bR1X,bR2X,bR3X,
                 r20X,r21X, fmA0,fmA1,fmB0,fmB1, acc1A,acc2A,acc1B,acc2B, s1A,s1B);
    int n2 = nbeg + ((s+2 < 18) ? (s+2)*32 : 0);
    ATTN_LOAD(X, n2)
    attn_compute(fa00Y,fa01Y,fa10Y,fa11Y, bL0Y,bL1Y,bL2Y,bL3Y, bR0Y,bR1Y,bR2Y,bR3Y,
                 r20Y,r21Y, fmA0,fmA1,fmB0,fmB1, acc1A,acc2A,acc1B,acc2B, s1A,s1B);
  }

  // ---- S1 block reduction ----
  s1A += __shfl_xor(s1A, 16, 64);  s1A += __shfl_xor(s1A, 32, 64);
  s1B += __shfl_xor(s1B, 16, 64);  s1B += __shfl_xor(s1B, 32, 64);
  if (lane < 16){ s1part[wv][lane] = s1A; s1part[wv][16+lane] = s1B; }
  __syncthreads();
  if (threadIdx.x < 32){
    int t = threadIdx.x;
    float s = s1part[0][t] + s1part[1][t] + s1part[2][t] + s1part[3][t];
    rs1inv[t] = 1.0f / s;
  }
  __syncthreads();

  float* B1 = (float*)(ws + OFF_B1) + (size_t)b*CH*HW;
  float* B2 = (float*)(ws + OFF_B2) + (size_t)b*CH*HW;
  int rl = threadIdx.x & 63;
  int rv = threadIdx.x >> 6;

  // 4 reduce phases: acc1A (scaled by rs1), acc2A, acc1B (scaled), acc2B
  #pragma unroll
  for (int v=0; v<16; ++v) red[wv][lane][v] = acc1A[v>>2][v&3];
  __syncthreads();
  #pragma unroll
  for (int k=0;k<4;k++){
    int v = rv + 4*k;
    float s = red[0][rl][v] + red[1][rl][v] + red[2][rl][v] + red[3][rl][v];
    int midx = ((rl>>4)<<2) + (v&3);
    int c = ((v>>2)<<4) + (rl & 15);
    B1[(size_t)c*HW + m0 + midx] = s * rs1inv[midx];
  }
  __syncthreads();
  #pragma unroll
  for (int v=0; v<16; ++v) red[wv][lane][v] = acc2A[v>>2][v&3];
  __syncthreads();
  #pragma unroll
  for (int k=0;k<4;k++){
    int v = rv + 4*k;
    float s = red[0][rl][v] + red[1][rl][v] + red[2][rl][v] + red[3][rl][v];
    int midx = ((rl>>4)<<2) + (v&3);
    int c = ((v>>2)<<4) + (rl & 15);
    B2[(size_t)c*HW + m0 + midx] = s;
  }
  __syncthreads();
  #pragma unroll
  for (int v=0; v<16; ++v) red[wv][lane][v] = acc1B[v>>2][v&3];
  __syncthreads();
  #pragma unroll
  for (int k=0;k<4;k++){
    int v = rv + 4*k;
    float s = red[0][rl][v] + red[1][rl][v] + red[2][rl][v] + red[3][rl][v];
    int midx = ((rl>>4)<<2) + (v&3);
    int c = ((v>>2)<<4) + (rl & 15);
    B1[(size_t)c*HW + m0 + 16 + midx] = s * rs1inv[16 + midx];
  }
  __syncthreads();
  #pragma unroll
  for (int v=0; v<16; ++v) red[wv][lane][v] = acc2B[v>>2][v&3];
  __syncthreads();
  #pragma unroll
  for (int k=0;k<4;k++){
    int v = rv + 4*k;
    float s = red[0][rl][v] + red[1][rl][v] + red[2][rl][v] + red[3][rl][v];
    int midx = ((rl>>4)<<2) + (v&3);
    int c = ((v>>2)<<4) + (rl & 15);
    B2[(size_t)c*HW + m0 + 16 + midx] = s;
  }
}

// ---------------- K4: gate + output convs (raw f32 weights), f32 OUTPUT ----------------
// 1-D grid 576: b = bid%8 (XCD affinity); q = bid/8: side=q&1, p0=(q>>1)*64
__global__ __launch_bounds__(256) void k_out(
    char* ws,
    const float* gwL, const float* gbL, const float* gwR, const float* gbR,
    const float* wLo, const float* bLoi, const float* wRo, const float* bRoi,
    float* out)
{
  __shared__ float xT[64][64];
  __shared__ float bT[64][64];
  __shared__ float gpart[4][64];
  __shared__ float gLds[64];
  int bid = blockIdx.x;
  int b   = bid & 7;
  int q   = bid >> 3;
  int side= q & 1;
  int p0  = (q >> 1) * 64;
  int t = threadIdx.x;
  const float* braw = (const float*)(ws + (side ? OFF_B2 : OFF_B1)) + (size_t)b*CH*HW;
  const u16*   xc   = (const u16*)(ws + (side ? OFF_XRC : OFF_XLC)) + (size_t)b*CH*HW;
  const float* w    = side ? wRo : wLo;
  const float* gw   = side ? gwR : gwL;
  float        gb   = side ? gbR[0] : gbL[0];
  const float* bias = side ? bRoi : bLoi;

  #pragma unroll
  for (int i=0;i<16;i++){
    int flat = i*256 + t;
    int c = flat >> 6, pl = flat & 63;
    bT[c][pl] = braw[(size_t)c*HW + p0 + pl];
    xT[c][pl] = bf2f(xc[(size_t)c*HW + p0 + pl]);
  }
  __syncthreads();
  {
    int qq = t >> 6, pl = t & 63;
    float a = 0.f;
    #pragma unroll
    for (int c = 0; c < 16; c++) a = fmaf(gw[16*qq + c], bT[16*qq + c][pl], a);
    gpart[qq][pl] = a;
  }
  __syncthreads();
  if (t < 64){
    float x = gpart[0][t]+gpart[1][t]+gpart[2][t]+gpart[3][t] + gb;
    gLds[t] = 1.0f/(1.0f + exp2f(-x*L2E));    // sigmoid
  }
  __syncthreads();
  #pragma unroll
  for (int i=0;i<16;i++){
    int flat = i*256 + t;
    int c = flat >> 6, pl = flat & 63;
    bT[c][pl] *= gLds[pl];
  }
  __syncthreads();
  int wv = t >> 6;
  int lane = t & 63;
  float* outp = out + ((size_t)side*B_ + b)*CH*HW;
  for (int oi=0; oi<16; oi++){
    int o = wv*16 + oi;
    float a = bias[o];
    #pragma unroll 8
    for (int c=0;c<64;c++){
      a = fmaf(w[o*128 + c],      xT[c][lane], a);
      a = fmaf(w[o*128 + 64 + c], bT[c][lane], a);
    }
    outp[(size_t)o*HW + p0 + lane] = a;
  }
}

extern "C" void kernel_launch(void* const* d_in, const int* in_sizes, int n_in,
                              void* d_out, int out_size, void* d_ws, size_t ws_size,
                              hipStream_t stream)
{
  char* ws = (char*)d_ws;
  k_proj <<<288, 256, 0, stream>>>(
      (const float*)d_in[0], (const float*)d_in[1],
      (const float*)d_in[2], (const float*)d_in[3],
      (const float*)d_in[4], (const float*)d_in[5],
      (const float*)d_in[6], (const float*)d_in[7], ws);
  k_stats<<<1152, 256, 0, stream>>>(ws);
  k_attn <<<576, 256, 0, stream>>>(ws);
  k_out  <<<576, 256, 0, stream>>>(
      ws,
      (const float*)d_in[8],  (const float*)d_in[9],
      (const float*)d_in[10], (const float*)d_in[11],
      (const float*)d_in[12], (const float*)d_in[13],
      (const float*)d_in[14], (const float*)d_in[15],
      (float*)d_out);
}